// Round 7
// baseline (195.668 us; speedup 1.0000x reference)
//
#include <hip/hip_runtime.h>
#include <math.h>

#define EE 300
#define KP 320     // bf16 row stride (10 k-steps of 32)
#define LDSW 328   // padded LDS row stride in shorts
#define QQ 64
#define DD 4096
#define NEG 0.01f

typedef __attribute__((ext_vector_type(8))) short short8;
typedef __attribute__((ext_vector_type(4))) float f32x4;
typedef unsigned short ushort_t;

__device__ inline ushort_t f2bf(float f) {
  unsigned u = __builtin_bit_cast(unsigned, f);
  u += 0x7fff + ((u >> 16) & 1);   // RNE
  return (ushort_t)(u >> 16);
}
__device__ inline float bf2f(ushort_t h) {
  return __builtin_bit_cast(float, (unsigned)h << 16);
}
__device__ inline void top5_insert(float* t, float v) {
  if (v > t[4]) {
    t[4] = v;
    #pragma unroll
    for (int j = 4; j > 0; --j)
      if (t[j] > t[j - 1]) { float tmp = t[j]; t[j] = t[j - 1]; t[j - 1] = tmp; }
  }
}

// ======== launch 1: gather+convert | weight frags | zero accum+counters =====
#define GATHER_ROWS (66 + 4098 + 4098)           // 8262
#define GATHER_BLOCKS ((GATHER_ROWS + 3) / 4)    // 2066
#define WT_BLOCKS 143                            // 570 frags / 4
#define ZERO_BLOCKS 9                            // 8320 floats + 8 counters
#define PREP_BLOCKS (GATHER_BLOCKS + WT_BLOCKS + ZERO_BLOCKS)

__global__ __launch_bounds__(256) void prep(
    const float* __restrict__ emb, const int* __restrict__ question,
    const int* __restrict__ doc1, const int* __restrict__ doc2,
    const float* __restrict__ conv_w,
    ushort_t* __restrict__ qbe, ushort_t* __restrict__ d1be, ushort_t* __restrict__ d2be,
    ushort_t* __restrict__ qbc, ushort_t* __restrict__ d1bc, ushort_t* __restrict__ d2bc,
    ushort_t* __restrict__ wt2,
    float* __restrict__ nq2, float* __restrict__ nd12, float* __restrict__ nd22,
    float* __restrict__ zero_base, unsigned* __restrict__ cnts) {
  int b = blockIdx.x;
  int tid = threadIdx.x;
  int wv = tid >> 6, lane = tid & 63;
  if (b < GATHER_BLOCKS) {
    int g = b * 4 + wv;
    if (g >= GATHER_ROWS) return;
    int t, row;
    if (g < 66)             { t = 0; row = g; }
    else if (g < 66 + 4098) { t = 1; row = g - 66; }
    else                    { t = 2; row = g - 4164; }
    const int* idx = t == 0 ? question : (t == 1 ? doc1 : doc2);
    int L = t == 0 ? QQ : DD;
    ushort_t* be = t == 0 ? qbe : (t == 1 ? d1be : d2be);
    ushort_t* bc = t == 0 ? qbc : (t == 1 ? d1bc : d2bc);
    float* nrm2 = t == 0 ? nq2 : (t == 1 ? nd12 : nd22);
    if (row == 0 || row == L + 1) {            // zero guard rows
      for (int i = lane; i < KP; i += 64) be[(size_t)row * KP + i] = 0;
      return;
    }
    int r = row - 1;
    const float* src = emb + (size_t)idx[r] * EE;
    float ss = 0.f;
    for (int i = lane; i < EE; i += 64) {
      float v = src[i];
      be[(size_t)row * KP + i] = f2bf(v);
      ss += v * v;
    }
    for (int i = EE + lane; i < KP; i += 64) {   // zero K-pads
      be[(size_t)row * KP + i] = 0;
      bc[(size_t)r * KP + i] = 0;
    }
    #pragma unroll
    for (int o = 32; o; o >>= 1) ss += __shfl_xor(ss, o);
    if (lane == 0) nrm2[r] = ss;                 // SQUARED norm
  } else if (b < GATHER_BLOCKS + WT_BLOCKS) {
    int f = (b - GATHER_BLOCKS) * 4 + wv;
    if (f >= 570) return;
    int ks = f % 10, n = (f / 10) % 19, tap = f / 190;
    int o = n * 16 + (lane & 15);
    int kbase = ks * 32 + (lane >> 4) * 8;
    ushort_t* dst = wt2 + (size_t)f * 512 + lane * 8;
    #pragma unroll
    for (int e = 0; e < 8; ++e) {
      int k = kbase + e;
      float v = (o < EE && k < EE) ? conv_w[((size_t)o * EE + k) * 3 + tap] : 0.f;
      dst[e] = f2bf(v);
    }
  } else {
    int zb = b - (GATHER_BLOCKS + WT_BLOCKS);
    if (zb == 0 && tid < 8) cnts[tid] = 0u;
    int i0 = zb * 1024 + tid;
    #pragma unroll
    for (int j = 0; j < 4; ++j) {
      int i = i0 + j * 256;
      if (i < 8320) zero_base[i] = 0.f;   // nqc2,nd1c2,nd2c2,qwacc contiguous
    }
  }
}

// ===== launch 2: conv1d(E,E,3,SAME)+bias+leaky+residual + norms^2 + qw-dot ==
__global__ __launch_bounds__(256) void conv_mfma(
    const ushort_t* __restrict__ wt2, const float* __restrict__ bias,
    const float* __restrict__ qw_w,
    const ushort_t* __restrict__ qbe, const ushort_t* __restrict__ d1be,
    const ushort_t* __restrict__ d2be,
    ushort_t* __restrict__ qbc, ushort_t* __restrict__ d1bc,
    ushort_t* __restrict__ d2bc,
    float* __restrict__ nqc2, float* __restrict__ nd1c2, float* __restrict__ nd2c2,
    float* __restrict__ qwacc) {
  __shared__ ushort_t lds[34 * LDSW];
  int bx = blockIdx.x;
  int t, m0, yh;
  if (bx < 4) { t = 0; m0 = (bx >> 1) * 32; yh = bx & 1; }
  else {
    int i = bx - 4;
    t = 1 + (i >> 8);
    int j = i & 255;
    m0 = (j >> 1) * 32; yh = j & 1;
  }
  const ushort_t* be = t == 0 ? qbe : (t == 1 ? d1be : d2be);
  ushort_t* bc = t == 0 ? qbc : (t == 1 ? d1bc : d2bc);
  float* nc2 = t == 0 ? nqc2 : (t == 1 ? nd1c2 : nd2c2);
  int tid = threadIdx.x;
  for (int s = tid; s < 34 * 40; s += 256) {
    int row = s / 40, col = s - row * 40;
    *(short8*)(&lds[row * LDSW + col * 8]) =
        *(const short8*)(be + (size_t)(m0 + row) * KP + col * 8);
  }
  __syncthreads();
  int wv = tid >> 6, lane = tid & 63, mrow = lane & 15, g = lane >> 4;
  int nstart, ncnt;
  if (yh == 0) { nstart = (wv < 2) ? 3 * wv : 2 * wv + 2; ncnt = (wv < 2) ? 3 : 2; }
  else         { nstart = (wv == 0) ? 10 : 2 * wv + 11;   ncnt = (wv == 0) ? 3 : 2; }
  f32x4 acc[3][2];
  #pragma unroll
  for (int j = 0; j < 3; ++j)
    #pragma unroll
    for (int h = 0; h < 2; ++h) acc[j][h] = (f32x4){0.f, 0.f, 0.f, 0.f};

  for (int tap = 0; tap < 3; ++tap) {
    const ushort_t* alo = &lds[(mrow + tap) * LDSW + g * 8];
    #pragma unroll
    for (int ks = 0; ks < 10; ++ks) {
      short8 a0 = *(const short8*)(alo + ks * 32);
      short8 a1 = *(const short8*)(alo + 16 * LDSW + ks * 32);
      #pragma unroll
      for (int j = 0; j < 3; ++j) {
        if (j < ncnt) {
          short8 bfr = *(const short8*)(wt2 +
              (size_t)((tap * 19 + nstart + j) * 10 + ks) * 512 + lane * 8);
          acc[j][0] = __builtin_amdgcn_mfma_f32_16x16x32_bf16(a0, bfr, acc[j][0], 0, 0, 0);
          acc[j][1] = __builtin_amdgcn_mfma_f32_16x16x32_bf16(a1, bfr, acc[j][1], 0, 0, 0);
        }
      }
    }
  }
  float ss[2][4] = {{0.f,0.f,0.f,0.f},{0.f,0.f,0.f,0.f}};
  float yq[2][4] = {{0.f,0.f,0.f,0.f},{0.f,0.f,0.f,0.f}};
  #pragma unroll
  for (int j = 0; j < 3; ++j) {
    if (j < ncnt) {
      int col = (nstart + j) * 16 + mrow;
      if (col < EE) {
        float bcol = bias[col];
        float qwc = (t == 0) ? qw_w[col] : 0.f;
        #pragma unroll
        for (int h = 0; h < 2; ++h) {
          #pragma unroll
          for (int r = 0; r < 4; ++r) {
            int lrow = h * 16 + g * 4 + r;
            float y = acc[j][h][r] + bcol;
            y = (y >= 0.f) ? y : NEG * y;
            y += bf2f(lds[(1 + lrow) * LDSW + col]);
            bc[(size_t)(m0 + lrow) * KP + col] = f2bf(y);
            ss[h][r] += y * y;
            if (t == 0) yq[h][r] += y * qwc;
          }
        }
      }
    }
  }
  #pragma unroll
  for (int h = 0; h < 2; ++h) {
    #pragma unroll
    for (int r = 0; r < 4; ++r) {
      float s = ss[h][r];
      s += __shfl_xor(s, 1); s += __shfl_xor(s, 2);
      s += __shfl_xor(s, 4); s += __shfl_xor(s, 8);
      if (mrow == 0) atomicAdd(&nc2[m0 + h * 16 + g * 4 + r], s);
      if (t == 0) {
        float sq = yq[h][r];
        sq += __shfl_xor(sq, 1); sq += __shfl_xor(sq, 2);
        sq += __shfl_xor(sq, 4); sq += __shfl_xor(sq, 8);
        if (mrow == 0) atomicAdd(&qwacc[m0 + h * 16 + g * 4 + r], sq);
      }
    }
  }
}

// ========== launch 3: sims GEMM + per-chunk top5 + merge + final ===========
// tasks 0..511: GEMM sims (s=task>>7, 32-l chunk), pool own strip.
// tasks 512..767: oh pooling from doc_sim row-chunks (coalesced, no transpose).
// pt5[psrc][q][chunk][8]: partial sorted top5 (desc, slots 5..7 = -1e30).
// cnts[ps] == 127 elects per-src merger; cnts[6] == 5 elects final block.
__global__ __launch_bounds__(256) void simpoolfinal(
    const ushort_t* __restrict__ qbe, const ushort_t* __restrict__ d1be,
    const ushort_t* __restrict__ d2be,
    const ushort_t* __restrict__ qbc, const ushort_t* __restrict__ d1bc,
    const ushort_t* __restrict__ d2bc,
    const float* __restrict__ nq2, const float* __restrict__ nd12,
    const float* __restrict__ nd22, const float* __restrict__ nqc2,
    const float* __restrict__ nd1c2, const float* __restrict__ nd2c2,
    const float* __restrict__ d1sim, const float* __restrict__ d2sim,
    float* __restrict__ pt5, unsigned* __restrict__ cnts, float* __restrict__ pool,
    const float* __restrict__ qwacc, const float* __restrict__ idf,
    const int* __restrict__ question, const float* __restrict__ qw_w,
    const float* __restrict__ qw_b, const float* __restrict__ lin1_w,
    const float* __restrict__ lin2_w, const float* __restrict__ out_w,
    const float* __restrict__ gaf, const float* __restrict__ baf,
    float* __restrict__ out5) {
  __shared__ ushort_t ldsB[32 * LDSW];
  __shared__ float strip[64][33];
  __shared__ unsigned oldv;
  int task = blockIdx.x;
  int tid = threadIdx.x;
  int wv = tid >> 6, lane = tid & 63;
  int ps, chunk;

  if (task < 512) {
    // ---- GEMM sims: s: 0=ins_d1 1=ins_d2 2=sen_d1 3=sen_d2 ----
    int s = task >> 7;
    chunk = task & 127;
    ps = (s == 0) ? 1 : (s == 1) ? 4 : (s == 2) ? 2 : 5;
    int l0 = chunk * 32;
    const ushort_t* A = (s < 2) ? qbe + KP : qbc;
    const ushort_t* B = s == 0 ? d1be + KP : s == 1 ? d2be + KP
                      : s == 2 ? d1bc : d2bc;
    const float* na2 = (s < 2) ? nq2 : nqc2;
    const float* nb2 = s == 0 ? nd12 : s == 1 ? nd22 : s == 2 ? nd1c2 : nd2c2;
    for (int i = tid; i < 32 * 40; i += 256) {
      int row = i / 40, col = i - row * 40;
      *(short8*)(&ldsB[row * LDSW + col * 8]) =
          *(const short8*)(B + (size_t)(l0 + row) * KP + col * 8);
    }
    __syncthreads();
    int mrow = lane & 15, g = lane >> 4;
    f32x4 acc[2];
    acc[0] = (f32x4){0.f, 0.f, 0.f, 0.f};
    acc[1] = (f32x4){0.f, 0.f, 0.f, 0.f};
    const ushort_t* arow = A + (size_t)(wv * 16 + mrow) * KP + g * 8;
    #pragma unroll
    for (int ks = 0; ks < 10; ++ks) {
      short8 a = *(const short8*)(arow + ks * 32);
      #pragma unroll
      for (int n = 0; n < 2; ++n) {
        short8 bfr = *(const short8*)(&ldsB[(n * 16 + mrow) * LDSW + g * 8 + ks * 32]);
        acc[n] = __builtin_amdgcn_mfma_f32_16x16x32_bf16(a, bfr, acc[n], 0, 0, 0);
      }
    }
    #pragma unroll
    for (int n = 0; n < 2; ++n) {
      int l = n * 16 + mrow;
      float inb = rsqrtf(nb2[l0 + l]);
      #pragma unroll
      for (int r = 0; r < 4; ++r) {
        int q = wv * 16 + g * 4 + r;
        strip[q][l] = acc[n][r] * rsqrtf(na2[q]) * inb;
      }
    }
  } else {
    // ---- oh pooling source: rows [l0..l0+31] x 64 q, coalesced ----
    int o = (task - 512) >> 7;
    chunk = task & 127;
    ps = o ? 3 : 0;
    const float* dsim = o ? d2sim : d1sim;
    int l0 = chunk * 32;
    int r = tid >> 3, q0 = (tid & 7) * 8;
    const float* srcp = dsim + (size_t)(l0 + r) * QQ + q0;
    f32x4 v0 = *(const f32x4*)srcp;
    f32x4 v1 = *(const f32x4*)(srcp + 4);
    #pragma unroll
    for (int e = 0; e < 4; ++e) strip[q0 + e][r] = v0[e];
    #pragma unroll
    for (int e = 0; e < 4; ++e) strip[q0 + 4 + e][r] = v1[e];
  }
  __syncthreads();

  // ---- per-chunk top5 over the 32-l strip, one thread per q ----
  if (tid < 64) {
    float t5[5] = {-1e30f, -1e30f, -1e30f, -1e30f, -1e30f};
    #pragma unroll
    for (int l = 0; l < 32; ++l) top5_insert(t5, strip[tid][l]);
    float* dst = pt5 + (((size_t)ps * QQ + tid) * 128 + chunk) * 8;
    *(f32x4*)dst = (f32x4){t5[0], t5[1], t5[2], t5[3]};
    *(f32x4*)(dst + 4) = (f32x4){t5[4], -1e30f, -1e30f, -1e30f};
  }
  __threadfence();
  __syncthreads();
  if (tid == 0) oldv = atomicAdd(&cnts[ps], 1u);
  __syncthreads();
  if (oldv != 127u) return;

  // ---- merger for src ps: 4 waves x 16 q, 2 chunks per lane + xor-merge ----
  __threadfence();
  for (int i = 0; i < 16; ++i) {
    int q = wv * 16 + i;
    const float* p0 = pt5 + (((size_t)ps * QQ + q) * 128 + 2 * lane) * 8;
    float t5[5] = {-1e30f, -1e30f, -1e30f, -1e30f, -1e30f};
    #pragma unroll
    for (int c = 0; c < 2; ++c)
      #pragma unroll
      for (int j = 0; j < 5; ++j) top5_insert(t5, p0[c * 8 + j]);
    #pragma unroll
    for (int mask = 1; mask < 64; mask <<= 1) {
      float a[5], bb[5];
      #pragma unroll
      for (int j = 0; j < 5; ++j) { a[j] = t5[j]; bb[j] = __shfl_xor(t5[j], mask); }
      int ia = 0, ib = 0;
      #pragma unroll
      for (int j = 0; j < 5; ++j) t5[j] = (a[ia] >= bb[ib]) ? a[ia++] : bb[ib++];
    }
    if (lane == 0) {
      float sm = t5[0] + t5[1] + t5[2] + t5[3] + t5[4];
      pool[((size_t)ps * QQ + q) * 2 + 0] = t5[0];
      pool[((size_t)ps * QQ + q) * 2 + 1] = sm * 0.2f;
    }
  }
  __threadfence();
  __syncthreads();
  if (tid == 0) oldv = atomicAdd(&cnts[6], 1u);
  __syncthreads();
  if (oldv != 5u) return;

  // ---- final epilogue: softmax + MLP (one wave) ----
  __threadfence();
  if (tid < 64) {
    int q = tid;
    float s = qwacc[q] + qw_b[0] + idf[question[q]] * qw_w[EE];
    float m = s;
    #pragma unroll
    for (int o = 32; o; o >>= 1) m = fmaxf(m, __shfl_xor(m, o));
    float e = expf(s - m);
    float se = e;
    #pragma unroll
    for (int o = 32; o; o >>= 1) se += __shfl_xor(se, o);
    float qwgt = e / se;
    float emit[2];
    for (int doc = 0; doc < 2; ++doc) {
      float temp[6];
      #pragma unroll
      for (int j = 0; j < 3; ++j) {
        temp[2 * j]     = pool[(((size_t)doc * 3 + j) * QQ + q) * 2 + 0];
        temp[2 * j + 1] = pool[(((size_t)doc * 3 + j) * QQ + q) * 2 + 1];
      }
      float lo = 0.f;
      #pragma unroll
      for (int r = 0; r < 8; ++r) {
        float h = 0.f;
        #pragma unroll
        for (int c = 0; c < 6; ++c) h += lin1_w[r * 6 + c] * temp[c];
        h = (h >= 0.f) ? h : NEG * h;
        lo += lin2_w[r] * h;
      }
      lo *= qwgt;
      #pragma unroll
      for (int o = 32; o; o >>= 1) lo += __shfl_xor(lo, o);
      emit[doc] = lo / (float)QQ;
    }
    if (q == 0) {
      float good = out_w[0] * gaf[0] + out_w[1] * gaf[1] + out_w[2] * gaf[2] +
                   out_w[3] * gaf[3] + out_w[4] * emit[0];
      float bad  = out_w[0] * baf[0] + out_w[1] * baf[1] + out_w[2] * baf[2] +
                   out_w[3] * baf[3] + out_w[4] * emit[1];
      float l1 = fmaxf(0.f, -(good - bad) + 1.f);
      out5[0] = l1; out5[1] = good; out5[2] = bad; out5[3] = l1; out5[4] = l1;
    }
  }
}

extern "C" void kernel_launch(void* const* d_in, const int* in_sizes, int n_in,
                              void* d_out, int out_size, void* d_ws, size_t ws_size,
                              hipStream_t stream) {
  (void)in_sizes; (void)n_in; (void)out_size; (void)ws_size;
  const int* question   = (const int*)d_in[0];
  const int* doc1       = (const int*)d_in[1];
  const int* doc2       = (const int*)d_in[2];
  const float* doc1_sim = (const float*)d_in[3];
  const float* doc2_sim = (const float*)d_in[4];
  const float* gaf      = (const float*)d_in[5];
  const float* baf      = (const float*)d_in[6];
  const float* emb      = (const float*)d_in[7];
  const float* idf      = (const float*)d_in[8];
  const float* conv_w   = (const float*)d_in[9];
  const float* conv_b   = (const float*)d_in[10];
  const float* qw_w     = (const float*)d_in[11];
  const float* qw_b     = (const float*)d_in[12];
  const float* lin1_w   = (const float*)d_in[13];
  const float* lin2_w   = (const float*)d_in[14];
  const float* out_w    = (const float*)d_in[15];
  float* out = (float*)d_out;

  char* p = (char*)d_ws;
  ushort_t* qbe  = (ushort_t*)p; p += (size_t)(QQ + 2) * KP * 2;
  ushort_t* d1be = (ushort_t*)p; p += (size_t)(DD + 2) * KP * 2;
  ushort_t* d2be = (ushort_t*)p; p += (size_t)(DD + 2) * KP * 2;
  ushort_t* qbc  = (ushort_t*)p; p += (size_t)QQ * KP * 2;
  ushort_t* d1bc = (ushort_t*)p; p += (size_t)DD * KP * 2;
  ushort_t* d2bc = (ushort_t*)p; p += (size_t)DD * KP * 2;
  ushort_t* wt2  = (ushort_t*)p; p += (size_t)570 * 512 * 2;
  float* nq2   = (float*)p; p += QQ * 4;
  float* nd12  = (float*)p; p += DD * 4;
  float* nd22  = (float*)p; p += DD * 4;
  // zeroed-each-call accumulator block (contiguous 8320 floats)
  float* nqc2  = (float*)p; p += QQ * 4;
  float* nd1c2 = (float*)p; p += DD * 4;
  float* nd2c2 = (float*)p; p += DD * 4;
  float* qwacc = (float*)p; p += QQ * 4;
  float* pt5   = (float*)p; p += (size_t)6 * QQ * 128 * 8 * 4;
  float* pool  = (float*)p; p += 6 * QQ * 2 * 4;
  unsigned* cnts = (unsigned*)p; p += 8 * 4;

  prep<<<PREP_BLOCKS, 256, 0, stream>>>(
      emb, question, doc1, doc2, conv_w,
      qbe, d1be, d2be, qbc, d1bc, d2bc, wt2,
      nq2, nd12, nd22, nqc2, cnts);

  conv_mfma<<<516, 256, 0, stream>>>(
      wt2, conv_b, qw_w, qbe, d1be, d2be, qbc, d1bc, d2bc,
      nqc2, nd1c2, nd2c2, qwacc);

  simpoolfinal<<<768, 256, 0, stream>>>(
      qbe, d1be, d2be, qbc, d1bc, d2bc,
      nq2, nd12, nd22, nqc2, nd1c2, nd2c2,
      doc1_sim, doc2_sim, pt5, cnts, pool,
      qwacc, idf, question, qw_w, qw_b, lin1_w, lin2_w, out_w, gaf, baf, out);
}

// Round 8
// 57.586 us; speedup vs baseline: 3.3978x; 3.3978x over previous
//
#include <hip/hip_runtime.h>
#include <math.h>

#define EE 300
#define KP 320     // bf16 row stride (10 k-steps of 32)
#define LDSW 328   // padded LDS row stride in shorts
#define QQ 64
#define DD 4096
#define NEG 0.01f

typedef __attribute__((ext_vector_type(8))) short short8;
typedef __attribute__((ext_vector_type(4))) float f32x4;
typedef unsigned short ushort_t;

__device__ inline ushort_t f2bf(float f) {
  unsigned u = __builtin_bit_cast(unsigned, f);
  u += 0x7fff + ((u >> 16) & 1);   // RNE
  return (ushort_t)(u >> 16);
}
__device__ inline float bf2f(ushort_t h) {
  return __builtin_bit_cast(float, (unsigned)h << 16);
}
__device__ inline void top5_insert(float* t, float v) {
  if (v > t[4]) {
    t[4] = v;
    #pragma unroll
    for (int j = 4; j > 0; --j)
      if (t[j] > t[j - 1]) { float tmp = t[j]; t[j] = t[j - 1]; t[j - 1] = tmp; }
  }
}

// == launch 1: gather+convert | weight frags | zero accum | oh partial pool ==
#define GATHER_ROWS (66 + 4098 + 4098)           // 8262
#define GATHER_BLOCKS ((GATHER_ROWS + 3) / 4)    // 2066
#define WT_BLOCKS 143                            // 570 frags / 4
#define ZERO_BLOCKS 9                            // 8320 floats
#define OHPOOL_BLOCKS 256                        // 2 srcs x 128 chunks
#define PREP_BLOCKS (GATHER_BLOCKS + WT_BLOCKS + ZERO_BLOCKS + OHPOOL_BLOCKS)

__global__ __launch_bounds__(256) void prep(
    const float* __restrict__ emb, const int* __restrict__ question,
    const int* __restrict__ doc1, const int* __restrict__ doc2,
    const float* __restrict__ conv_w,
    const float* __restrict__ doc1_sim, const float* __restrict__ doc2_sim,
    ushort_t* __restrict__ qbe, ushort_t* __restrict__ d1be, ushort_t* __restrict__ d2be,
    ushort_t* __restrict__ qbc, ushort_t* __restrict__ d1bc, ushort_t* __restrict__ d2bc,
    ushort_t* __restrict__ wt2,
    float* __restrict__ nq2, float* __restrict__ nd12, float* __restrict__ nd22,
    float* __restrict__ zero_base, float* __restrict__ pt5) {
  __shared__ float strip[64][33];
  int b = blockIdx.x;
  int tid = threadIdx.x;
  int wv = tid >> 6, lane = tid & 63;
  if (b < GATHER_BLOCKS) {
    int g = b * 4 + wv;
    if (g >= GATHER_ROWS) return;
    int t, row;
    if (g < 66)             { t = 0; row = g; }
    else if (g < 66 + 4098) { t = 1; row = g - 66; }
    else                    { t = 2; row = g - 4164; }
    const int* idx = t == 0 ? question : (t == 1 ? doc1 : doc2);
    int L = t == 0 ? QQ : DD;
    ushort_t* be = t == 0 ? qbe : (t == 1 ? d1be : d2be);
    ushort_t* bc = t == 0 ? qbc : (t == 1 ? d1bc : d2bc);
    float* nrm2 = t == 0 ? nq2 : (t == 1 ? nd12 : nd22);
    if (row == 0 || row == L + 1) {            // zero guard rows
      for (int i = lane; i < KP; i += 64) be[(size_t)row * KP + i] = 0;
      return;
    }
    int r = row - 1;
    const float* src = emb + (size_t)idx[r] * EE;
    float ss = 0.f;
    for (int i = lane; i < EE; i += 64) {
      float v = src[i];
      be[(size_t)row * KP + i] = f2bf(v);
      ss += v * v;
    }
    for (int i = EE + lane; i < KP; i += 64) {   // zero K-pads
      be[(size_t)row * KP + i] = 0;
      bc[(size_t)r * KP + i] = 0;
    }
    #pragma unroll
    for (int o = 32; o; o >>= 1) ss += __shfl_xor(ss, o);
    if (lane == 0) nrm2[r] = ss;                 // SQUARED norm
  } else if (b < GATHER_BLOCKS + WT_BLOCKS) {
    int f = (b - GATHER_BLOCKS) * 4 + wv;
    if (f >= 570) return;
    int ks = f % 10, n = (f / 10) % 19, tap = f / 190;
    int o = n * 16 + (lane & 15);
    int kbase = ks * 32 + (lane >> 4) * 8;
    ushort_t* dst = wt2 + (size_t)f * 512 + lane * 8;
    #pragma unroll
    for (int e = 0; e < 8; ++e) {
      int k = kbase + e;
      float v = (o < EE && k < EE) ? conv_w[((size_t)o * EE + k) * 3 + tap] : 0.f;
      dst[e] = f2bf(v);
    }
  } else if (b < GATHER_BLOCKS + WT_BLOCKS + ZERO_BLOCKS) {
    int i0 = (b - (GATHER_BLOCKS + WT_BLOCKS)) * 1024 + tid;
    #pragma unroll
    for (int j = 0; j < 4; ++j) {
      int i = i0 + j * 256;
      if (i < 8320) zero_base[i] = 0.f;   // nqc2,nd1c2,nd2c2,qwacc contiguous
    }
  } else {
    // ---- oh partial pooling: coalesced 32-row x 64-q chunk of doc_sim ----
    int ob = b - (GATHER_BLOCKS + WT_BLOCKS + ZERO_BLOCKS);
    int o = ob >> 7, chunk = ob & 127;
    int ps = o ? 3 : 0;
    const float* dsim = o ? doc2_sim : doc1_sim;   // [D][Q]
    int l0 = chunk * 32;
    int r = tid >> 3, q0 = (tid & 7) * 8;
    const float* srcp = dsim + (size_t)(l0 + r) * QQ + q0;
    f32x4 v0 = *(const f32x4*)srcp;
    f32x4 v1 = *(const f32x4*)(srcp + 4);
    #pragma unroll
    for (int e = 0; e < 4; ++e) strip[q0 + e][r] = v0[e];
    #pragma unroll
    for (int e = 0; e < 4; ++e) strip[q0 + 4 + e][r] = v1[e];
    __syncthreads();
    if (tid < 64) {
      float t5[5] = {-1e30f, -1e30f, -1e30f, -1e30f, -1e30f};
      #pragma unroll
      for (int l = 0; l < 32; ++l) top5_insert(t5, strip[tid][l]);
      float* dst = pt5 + (((size_t)ps * QQ + tid) * 128 + chunk) * 8;
      *(f32x4*)dst = (f32x4){t5[0], t5[1], t5[2], t5[3]};
      *(f32x4*)(dst + 4) = (f32x4){t5[4], -1e30f, -1e30f, -1e30f};
    }
  }
}

// ===== launch 2: conv1d(E,E,3,SAME)+bias+leaky+residual + norms^2 + qw-dot ==
__global__ __launch_bounds__(256) void conv_mfma(
    const ushort_t* __restrict__ wt2, const float* __restrict__ bias,
    const float* __restrict__ qw_w,
    const ushort_t* __restrict__ qbe, const ushort_t* __restrict__ d1be,
    const ushort_t* __restrict__ d2be,
    ushort_t* __restrict__ qbc, ushort_t* __restrict__ d1bc,
    ushort_t* __restrict__ d2bc,
    float* __restrict__ nqc2, float* __restrict__ nd1c2, float* __restrict__ nd2c2,
    float* __restrict__ qwacc) {
  __shared__ ushort_t lds[34 * LDSW];
  int bx = blockIdx.x;
  int t, m0, yh;
  if (bx < 4) { t = 0; m0 = (bx >> 1) * 32; yh = bx & 1; }
  else {
    int i = bx - 4;
    t = 1 + (i >> 8);
    int j = i & 255;
    m0 = (j >> 1) * 32; yh = j & 1;
  }
  const ushort_t* be = t == 0 ? qbe : (t == 1 ? d1be : d2be);
  ushort_t* bc = t == 0 ? qbc : (t == 1 ? d1bc : d2bc);
  float* nc2 = t == 0 ? nqc2 : (t == 1 ? nd1c2 : nd2c2);
  int tid = threadIdx.x;
  for (int s = tid; s < 34 * 40; s += 256) {
    int row = s / 40, col = s - row * 40;
    *(short8*)(&lds[row * LDSW + col * 8]) =
        *(const short8*)(be + (size_t)(m0 + row) * KP + col * 8);
  }
  __syncthreads();
  int wv = tid >> 6, lane = tid & 63, mrow = lane & 15, g = lane >> 4;
  int nstart, ncnt;
  if (yh == 0) { nstart = (wv < 2) ? 3 * wv : 2 * wv + 2; ncnt = (wv < 2) ? 3 : 2; }
  else         { nstart = (wv == 0) ? 10 : 2 * wv + 11;   ncnt = (wv == 0) ? 3 : 2; }
  f32x4 acc[3][2];
  #pragma unroll
  for (int j = 0; j < 3; ++j)
    #pragma unroll
    for (int h = 0; h < 2; ++h) acc[j][h] = (f32x4){0.f, 0.f, 0.f, 0.f};

  for (int tap = 0; tap < 3; ++tap) {
    const ushort_t* alo = &lds[(mrow + tap) * LDSW + g * 8];
    #pragma unroll
    for (int ks = 0; ks < 10; ++ks) {
      short8 a0 = *(const short8*)(alo + ks * 32);
      short8 a1 = *(const short8*)(alo + 16 * LDSW + ks * 32);
      #pragma unroll
      for (int j = 0; j < 3; ++j) {
        if (j < ncnt) {
          short8 bfr = *(const short8*)(wt2 +
              (size_t)((tap * 19 + nstart + j) * 10 + ks) * 512 + lane * 8);
          acc[j][0] = __builtin_amdgcn_mfma_f32_16x16x32_bf16(a0, bfr, acc[j][0], 0, 0, 0);
          acc[j][1] = __builtin_amdgcn_mfma_f32_16x16x32_bf16(a1, bfr, acc[j][1], 0, 0, 0);
        }
      }
    }
  }
  float ss[2][4] = {{0.f,0.f,0.f,0.f},{0.f,0.f,0.f,0.f}};
  float yq[2][4] = {{0.f,0.f,0.f,0.f},{0.f,0.f,0.f,0.f}};
  #pragma unroll
  for (int j = 0; j < 3; ++j) {
    if (j < ncnt) {
      int col = (nstart + j) * 16 + mrow;
      if (col < EE) {
        float bcol = bias[col];
        float qwc = (t == 0) ? qw_w[col] : 0.f;
        #pragma unroll
        for (int h = 0; h < 2; ++h) {
          #pragma unroll
          for (int r = 0; r < 4; ++r) {
            int lrow = h * 16 + g * 4 + r;
            float y = acc[j][h][r] + bcol;
            y = (y >= 0.f) ? y : NEG * y;
            y += bf2f(lds[(1 + lrow) * LDSW + col]);
            bc[(size_t)(m0 + lrow) * KP + col] = f2bf(y);
            ss[h][r] += y * y;
            if (t == 0) yq[h][r] += y * qwc;
          }
        }
      }
    }
  }
  #pragma unroll
  for (int h = 0; h < 2; ++h) {
    #pragma unroll
    for (int r = 0; r < 4; ++r) {
      float s = ss[h][r];
      s += __shfl_xor(s, 1); s += __shfl_xor(s, 2);
      s += __shfl_xor(s, 4); s += __shfl_xor(s, 8);
      if (mrow == 0) atomicAdd(&nc2[m0 + h * 16 + g * 4 + r], s);
      if (t == 0) {
        float sq = yq[h][r];
        sq += __shfl_xor(sq, 1); sq += __shfl_xor(sq, 2);
        sq += __shfl_xor(sq, 4); sq += __shfl_xor(sq, 8);
        if (mrow == 0) atomicAdd(&qwacc[m0 + h * 16 + g * 4 + r], sq);
      }
    }
  }
}

// ====== launch 3: sims GEMM + per-chunk partial top5 (no global sims) =======
// 512 blocks: s = b>>7 (0=ins_d1 1=ins_d2 2=sen_d1 3=sen_d2), chunk = b&127.
__global__ __launch_bounds__(256) void sim_pool(
    const ushort_t* __restrict__ qbe, const ushort_t* __restrict__ d1be,
    const ushort_t* __restrict__ d2be,
    const ushort_t* __restrict__ qbc, const ushort_t* __restrict__ d1bc,
    const ushort_t* __restrict__ d2bc,
    const float* __restrict__ nq2, const float* __restrict__ nd12,
    const float* __restrict__ nd22, const float* __restrict__ nqc2,
    const float* __restrict__ nd1c2, const float* __restrict__ nd2c2,
    float* __restrict__ pt5) {
  __shared__ ushort_t ldsB[32 * LDSW];
  __shared__ float strip[64][33];
  int s = blockIdx.x >> 7, chunk = blockIdx.x & 127;
  int ps = (s == 0) ? 1 : (s == 1) ? 4 : (s == 2) ? 2 : 5;
  int l0 = chunk * 32;
  const ushort_t* A = (s < 2) ? qbe + KP : qbc;
  const ushort_t* B = s == 0 ? d1be + KP : s == 1 ? d2be + KP
                    : s == 2 ? d1bc : d2bc;
  const float* na2 = (s < 2) ? nq2 : nqc2;
  const float* nb2 = s == 0 ? nd12 : s == 1 ? nd22 : s == 2 ? nd1c2 : nd2c2;
  int tid = threadIdx.x;
  for (int i = tid; i < 32 * 40; i += 256) {
    int row = i / 40, col = i - row * 40;
    *(short8*)(&ldsB[row * LDSW + col * 8]) =
        *(const short8*)(B + (size_t)(l0 + row) * KP + col * 8);
  }
  __syncthreads();
  int wv = tid >> 6, lane = tid & 63, mrow = lane & 15, g = lane >> 4;
  f32x4 acc[2];
  acc[0] = (f32x4){0.f, 0.f, 0.f, 0.f};
  acc[1] = (f32x4){0.f, 0.f, 0.f, 0.f};
  const ushort_t* arow = A + (size_t)(wv * 16 + mrow) * KP + g * 8;
  #pragma unroll
  for (int ks = 0; ks < 10; ++ks) {
    short8 a = *(const short8*)(arow + ks * 32);
    #pragma unroll
    for (int n = 0; n < 2; ++n) {
      short8 bfr = *(const short8*)(&ldsB[(n * 16 + mrow) * LDSW + g * 8 + ks * 32]);
      acc[n] = __builtin_amdgcn_mfma_f32_16x16x32_bf16(a, bfr, acc[n], 0, 0, 0);
    }
  }
  #pragma unroll
  for (int n = 0; n < 2; ++n) {
    int l = n * 16 + mrow;
    float inb = rsqrtf(nb2[l0 + l]);
    #pragma unroll
    for (int r = 0; r < 4; ++r) {
      int q = wv * 16 + g * 4 + r;
      strip[q][l] = acc[n][r] * rsqrtf(na2[q]) * inb;
    }
  }
  __syncthreads();
  if (tid < 64) {
    float t5[5] = {-1e30f, -1e30f, -1e30f, -1e30f, -1e30f};
    #pragma unroll
    for (int l = 0; l < 32; ++l) top5_insert(t5, strip[tid][l]);
    float* dst = pt5 + (((size_t)ps * QQ + tid) * 128 + chunk) * 8;
    *(f32x4*)dst = (f32x4){t5[0], t5[1], t5[2], t5[3]};
    *(f32x4*)(dst + 4) = (f32x4){t5[4], -1e30f, -1e30f, -1e30f};
  }
}

// ========= launch 4: merge 128 partials per (src,q) -> pool ================
// 96 blocks x 4 waves; wave = one (src,q). Coalesced 4KB read per wave.
__global__ __launch_bounds__(256) void merge(
    const float* __restrict__ pt5, float* __restrict__ pool) {
  int widx = blockIdx.x * 4 + (threadIdx.x >> 6);
  int lane = threadIdx.x & 63;
  int src = widx >> 6, q = widx & 63;
  const float* p0 = pt5 + (((size_t)src * QQ + q) * 128 + 2 * lane) * 8;
  float t5[5] = {-1e30f, -1e30f, -1e30f, -1e30f, -1e30f};
  #pragma unroll
  for (int c = 0; c < 2; ++c)
    #pragma unroll
    for (int j = 0; j < 5; ++j) top5_insert(t5, p0[c * 8 + j]);
  #pragma unroll
  for (int mask = 1; mask < 64; mask <<= 1) {
    float a[5], bb[5];
    #pragma unroll
    for (int j = 0; j < 5; ++j) { a[j] = t5[j]; bb[j] = __shfl_xor(t5[j], mask); }
    int ia = 0, ib = 0;
    #pragma unroll
    for (int j = 0; j < 5; ++j) t5[j] = (a[ia] >= bb[ib]) ? a[ia++] : bb[ib++];
  }
  if (lane == 0) {
    float sm = t5[0] + t5[1] + t5[2] + t5[3] + t5[4];
    pool[((size_t)src * QQ + q) * 2 + 0] = t5[0];
    pool[((size_t)src * QQ + q) * 2 + 1] = sm * 0.2f;
  }
}

// ================= launch 5: softmax + MLP + epilogue (one wave) ============
__global__ void final_kernel(
    const float* __restrict__ qwacc, const float* __restrict__ idf,
    const int* __restrict__ question, const float* __restrict__ qw_w,
    const float* __restrict__ qw_b, const float* __restrict__ pool,
    const float* __restrict__ lin1_w, const float* __restrict__ lin2_w,
    const float* __restrict__ out_w, const float* __restrict__ gaf,
    const float* __restrict__ baf, float* __restrict__ out5) {
  int q = threadIdx.x;  // 64 threads = one wave
  float s = qwacc[q] + qw_b[0] + idf[question[q]] * qw_w[EE];
  float m = s;
  #pragma unroll
  for (int o = 32; o; o >>= 1) m = fmaxf(m, __shfl_xor(m, o));
  float e = expf(s - m);
  float se = e;
  #pragma unroll
  for (int o = 32; o; o >>= 1) se += __shfl_xor(se, o);
  float qwgt = e / se;

  float emit[2];
  for (int doc = 0; doc < 2; ++doc) {
    float temp[6];
    #pragma unroll
    for (int j = 0; j < 3; ++j) {
      temp[2 * j]     = pool[(((size_t)doc * 3 + j) * QQ + q) * 2 + 0];
      temp[2 * j + 1] = pool[(((size_t)doc * 3 + j) * QQ + q) * 2 + 1];
    }
    float lo = 0.f;
    #pragma unroll
    for (int r = 0; r < 8; ++r) {
      float h = 0.f;
      #pragma unroll
      for (int c = 0; c < 6; ++c) h += lin1_w[r * 6 + c] * temp[c];
      h = (h >= 0.f) ? h : NEG * h;
      lo += lin2_w[r] * h;
    }
    lo *= qwgt;
    #pragma unroll
    for (int o = 32; o; o >>= 1) lo += __shfl_xor(lo, o);
    emit[doc] = lo / (float)QQ;
  }
  if (q == 0) {
    float good = out_w[0] * gaf[0] + out_w[1] * gaf[1] + out_w[2] * gaf[2] +
                 out_w[3] * gaf[3] + out_w[4] * emit[0];
    float bad  = out_w[0] * baf[0] + out_w[1] * baf[1] + out_w[2] * baf[2] +
                 out_w[3] * baf[3] + out_w[4] * emit[1];
    float l1 = fmaxf(0.f, -(good - bad) + 1.f);
    out5[0] = l1; out5[1] = good; out5[2] = bad; out5[3] = l1; out5[4] = l1;
  }
}

extern "C" void kernel_launch(void* const* d_in, const int* in_sizes, int n_in,
                              void* d_out, int out_size, void* d_ws, size_t ws_size,
                              hipStream_t stream) {
  (void)in_sizes; (void)n_in; (void)out_size; (void)ws_size;
  const int* question   = (const int*)d_in[0];
  const int* doc1       = (const int*)d_in[1];
  const int* doc2       = (const int*)d_in[2];
  const float* doc1_sim = (const float*)d_in[3];
  const float* doc2_sim = (const float*)d_in[4];
  const float* gaf      = (const float*)d_in[5];
  const float* baf      = (const float*)d_in[6];
  const float* emb      = (const float*)d_in[7];
  const float* idf      = (const float*)d_in[8];
  const float* conv_w   = (const float*)d_in[9];
  const float* conv_b   = (const float*)d_in[10];
  const float* qw_w     = (const float*)d_in[11];
  const float* qw_b     = (const float*)d_in[12];
  const float* lin1_w   = (const float*)d_in[13];
  const float* lin2_w   = (const float*)d_in[14];
  const float* out_w    = (const float*)d_in[15];
  float* out = (float*)d_out;

  char* p = (char*)d_ws;
  ushort_t* qbe  = (ushort_t*)p; p += (size_t)(QQ + 2) * KP * 2;
  ushort_t* d1be = (ushort_t*)p; p += (size_t)(DD + 2) * KP * 2;
  ushort_t* d2be = (ushort_t*)p; p += (size_t)(DD + 2) * KP * 2;
  ushort_t* qbc  = (ushort_t*)p; p += (size_t)QQ * KP * 2;
  ushort_t* d1bc = (ushort_t*)p; p += (size_t)DD * KP * 2;
  ushort_t* d2bc = (ushort_t*)p; p += (size_t)DD * KP * 2;
  ushort_t* wt2  = (ushort_t*)p; p += (size_t)570 * 512 * 2;
  float* nq2   = (float*)p; p += QQ * 4;
  float* nd12  = (float*)p; p += DD * 4;
  float* nd22  = (float*)p; p += DD * 4;
  // zeroed-each-call accumulator block (contiguous 8320 floats)
  float* nqc2  = (float*)p; p += QQ * 4;
  float* nd1c2 = (float*)p; p += DD * 4;
  float* nd2c2 = (float*)p; p += DD * 4;
  float* qwacc = (float*)p; p += QQ * 4;
  float* pt5   = (float*)p; p += (size_t)6 * QQ * 128 * 8 * 4;
  float* pool  = (float*)p; p += 6 * QQ * 2 * 4;

  prep<<<PREP_BLOCKS, 256, 0, stream>>>(
      emb, question, doc1, doc2, conv_w, doc1_sim, doc2_sim,
      qbe, d1be, d2be, qbc, d1bc, d2bc, wt2,
      nq2, nd12, nd22, nqc2, pt5);

  conv_mfma<<<516, 256, 0, stream>>>(
      wt2, conv_b, qw_w, qbe, d1be, d2be, qbc, d1bc, d2bc,
      nqc2, nd1c2, nd2c2, qwacc);

  sim_pool<<<512, 256, 0, stream>>>(
      qbe, d1be, d2be, qbc, d1bc, d2bc,
      nq2, nd12, nd22, nqc2, nd1c2, nd2c2, pt5);

  merge<<<96, 256, 0, stream>>>(pt5, pool);

  final_kernel<<<1, 64, 0, stream>>>(qwacc, idf, question, qw_w, qw_b, pool,
                                     lin1_w, lin2_w, out_w, gaf, baf, out);
}